// Round 3
// baseline (4172.269 us; speedup 1.0000x reference)
//
#include <hip/hip_runtime.h>
#include <hip/hip_bf16.h>
#include <stdint.h>

typedef __bf16 bf16_t;
typedef __bf16 bf16x8 __attribute__((ext_vector_type(8)));
typedef float f32x4 __attribute__((ext_vector_type(4)));

#define T_STEPS 64
#define BATCH   512
#define NTOKC   512
#define NINP    600
#define NHID    600
#define NBLK    6
#define BSZ     100
#define DK      64
#define ATTD    340
#define DC      32
#define KU_N    384     // 64 (k1) + 300 (u) + pad
#define OUT_KP  608     // NHID padded for dec GEMM K

// workspace layout (bytes), all 16B aligned
#define WS_KU     0u                 // 32768*384*4  = 50331648
#define WS_OUTB   50331648u          // 32768*608*2  = 39845888
#define WS_W1     90177536u          // 512*384*4    = 786432
#define WS_B1     90963968u          // 384*4        = 1536
#define WS_WVWX   90965504u          // 600*300*4    = 720000
#define WS_DECWT  91685504u          // 512*608*2    = 622592  (end ~92.3 MB)

// ---------------- prep kernels (tiny fp32 GEMMs) ----------------

__global__ void prep_wvwx(const float* __restrict__ Wv, const float* __restrict__ Wx,
                          float* __restrict__ WvWx) {
    int idx = blockIdx.x * 256 + threadIdx.x;
    if (idx >= NINP * 300) return;
    int i = idx / 300, c = idx % 300;
    float acc = 0.f;
    for (int a = 0; a < ATTD; a++) acc += Wv[i * ATTD + a] * Wx[a * 300 + c];
    WvWx[i * 300 + c] = acc;
}

__global__ void prep_w1(const float* __restrict__ encW, const float* __restrict__ Wk,
                        const float* __restrict__ WvWx, float* __restrict__ W1) {
    int idx = blockIdx.x * 256 + threadIdx.x;
    if (idx >= NTOKC * KU_N) return;
    int i = idx / KU_N, c = idx % KU_N;
    float acc = 0.f;
    if (c < DK) {
        for (int k = 0; k < NINP; k++) acc += encW[i * NINP + k] * Wk[k * DK + c];
    } else if (c < DK + 300) {
        int cc = c - DK;
        for (int k = 0; k < NINP; k++) acc += encW[i * NINP + k] * WvWx[k * 300 + cc];
    }
    W1[idx] = acc;
}

__global__ void prep_b1(const float* __restrict__ encB, const float* __restrict__ Wk,
                        const float* __restrict__ WvWx, float* __restrict__ b1) {
    int c = blockIdx.x * 256 + threadIdx.x;
    if (c >= KU_N) return;
    float acc = 0.f;
    if (c < DK) {
        for (int k = 0; k < NINP; k++) acc += encB[k] * Wk[k * DK + c];
    } else if (c < DK + 300) {
        int cc = c - DK;
        for (int k = 0; k < NINP; k++) acc += encB[k] * WvWx[k * 300 + cc];
    }
    b1[c] = acc;
}

__global__ void prep_decwt(const float* __restrict__ decW, bf16_t* __restrict__ decWT) {
    int idx = blockIdx.x * 256 + threadIdx.x;
    if (idx >= NTOKC * OUT_KP) return;
    int n = idx / OUT_KP, k = idx % OUT_KP;
    decWT[idx] = (k < NHID) ? (bf16_t)decW[k * NTOKC + n] : (bf16_t)0.f;
}

// ---------------- KU = input @ W1 + b1 (fp32; precision-critical) ----------------
// M=32768, K=512, N=384. BM=128 BN=64 BK=16, 256 thr, 8x4 per-thread tile.

__global__ __launch_bounds__(256) void ku_gemm(const float* __restrict__ A,
                                               const float* __restrict__ W1,
                                               const float* __restrict__ b1,
                                               float* __restrict__ KU) {
    __shared__ float As[16][128];
    __shared__ float Bs[16][64];
    const int tid = threadIdx.x;
    const int m0 = blockIdx.x * 128, n0 = blockIdx.y * 64;
    const int ty = tid >> 4, tx = tid & 15;
    const int bk = tid >> 6, bn = tid & 63;
    float acc[8][4] = {};
    for (int k0 = 0; k0 < NTOKC; k0 += 16) {
#pragma unroll
        for (int ii = 0; ii < 2; ii++) {
            int t2 = tid + ii * 256;
            int ar = t2 >> 2, ac4 = (t2 & 3) << 2;
            float4 raw = *(const float4*)(A + (size_t)(m0 + ar) * NTOKC + k0 + ac4);
            As[ac4 + 0][ar] = raw.x;
            As[ac4 + 1][ar] = raw.y;
            As[ac4 + 2][ar] = raw.z;
            As[ac4 + 3][ar] = raw.w;
        }
#pragma unroll
        for (int i = 0; i < 4; i++) {
            int kk = bk + (i << 2);
            Bs[kk][bn] = W1[(size_t)(k0 + kk) * KU_N + n0 + bn];
        }
        __syncthreads();
#pragma unroll
        for (int kk = 0; kk < 16; kk++) {
            float4 a0 = *(const float4*)&As[kk][ty * 8];
            float4 a1 = *(const float4*)&As[kk][ty * 8 + 4];
            float4 bv = *(const float4*)&Bs[kk][tx * 4];
            float av[8] = {a0.x, a0.y, a0.z, a0.w, a1.x, a1.y, a1.z, a1.w};
            float bw[4] = {bv.x, bv.y, bv.z, bv.w};
#pragma unroll
            for (int r = 0; r < 8; r++)
#pragma unroll
                for (int c = 0; c < 4; c++) acc[r][c] += av[r] * bw[c];
        }
        __syncthreads();
    }
#pragma unroll
    for (int r = 0; r < 8; r++) {
        int m = m0 + ty * 8 + r;
#pragma unroll
        for (int c = 0; c < 4; c++) {
            int n = n0 + tx * 4 + c;
            KU[(size_t)m * KU_N + n] = acc[r][c] + b1[n];
        }
    }
}

// ---------------- persistent scan: grid 256 (1 WG/CU, lockstep), 640 thr, 2 elems/WG ----
// Round-0 config (proven 27 MB FETCH: weights stay L2/LLC-hot only when all blocks
// move through phases in lockstep at 1 block/CU; 512-block grids exploded FETCH to
// 0.5-4.2 GB). Changes vs round 0: 10 -> 5 barriers/step, all serial micro-phases
// (12-thr dot, 72-thr logits, 12-thr softmax) wave-parallelized, q-GEMM replaced by
// per-wave q·k1 shfl-reduce jobs inside P1.

__global__ __launch_bounds__(640) void scan_kernel(
    const float* __restrict__ hidden, const float* __restrict__ masks,
    const float* __restrict__ Wq, const float* __restrict__ Wh,
    const float* __restrict__ grub, const float* __restrict__ Wq2,
    const float* __restrict__ Wk2, const float* __restrict__ Wv2,
    const float* __restrict__ KU, bf16_t* __restrict__ outb,
    float* __restrict__ hT_out, float* __restrict__ bm_out) {
    __shared__ float h[2][NHID];
    __shared__ float u[2][300];
    __shared__ float k1s[2][DK];
    __shared__ float p1s[2][NBLK], bmv[2][NBLK];
    __shared__ float hg[2][NBLK][300];   // hg, then hn in cols [0,100)
    __shared__ float qkv[2][NBLK][164];  // q2|k2|v2
    __shared__ float p2s[2][NBLK][6];

    const int tid = threadIdx.x;
    const int b0 = blockIdx.x * 2;

    // prologue: h pre-masked for t=0; KU row for t=0
    {
        float mv0 = masks[b0];
        float mv1 = masks[b0 + 1];
        for (int idx = tid; idx < 2 * NHID; idx += 640) {
            int b = idx / NHID, j = idx % NHID;
            h[b][j] = hidden[(size_t)(b0 + b) * NHID + j] * (b ? mv1 : mv0);
        }
        for (int idx = tid; idx < 2 * 364; idx += 640) {
            int b = idx / 364, c = idx % 364;
            float v = KU[(size_t)(b0 + b) * KU_N + c];
            if (c < DK) k1s[b][c] = v; else u[b][c - DK] = v;
        }
    }
    __syncthreads();

    for (int t = 0; t < T_STEPS; t++) {
        // ---- P1a: 12 per-wave score jobs: lane l holds q[b,n,l] = h[b,n*100:]·Wq[:,l],
        //           then s = sum_l q*k1[l] via shfl; p1 = sigmoid(s/8). No barrier inside.
        {
            int w = tid >> 6, l = tid & 63;
            for (int j = w; j < 12; j += 10) {
                int b = j / 6, n = j % 6;
                const float* hp = &h[b][n * BSZ];
                float a0 = 0.f, a1 = 0.f, a2 = 0.f, a3 = 0.f;
                for (int k = 0; k < BSZ; k += 4) {
                    a0 += hp[k + 0] * Wq[(k + 0) * DK + l];
                    a1 += hp[k + 1] * Wq[(k + 1) * DK + l];
                    a2 += hp[k + 2] * Wq[(k + 2) * DK + l];
                    a3 += hp[k + 3] * Wq[(k + 3) * DK + l];
                }
                float part = ((a0 + a1) + (a2 + a3)) * k1s[b][l];
                part += __shfl_down(part, 32);
                part += __shfl_down(part, 16);
                part += __shfl_down(part, 8);
                part += __shfl_down(part, 4);
                part += __shfl_down(part, 2);
                part += __shfl_down(part, 1);
                if (l == 0) {
                    float s = part * 0.125f;
                    float mx = fmaxf(s, 0.f);
                    float e0 = expf(0.f - mx), e1 = expf(s - mx);
                    p1s[b][n] = e1 / (e0 + e1);
                }
            }
        }
        // ---- P1b: hg = h @ Wh  (600 threads, 6 accs each; round-0 proven shape)
        for (int idx = tid; idx < 600; idx += 640) {
            int b = idx / 300, c = idx % 300;
            float acc[NBLK] = {};
            for (int k = 0; k < BSZ; k += 4) {
                float w0 = Wh[(k)*300 + c];
                float w1 = Wh[(k + 1) * 300 + c];
                float w2 = Wh[(k + 2) * 300 + c];
                float w3 = Wh[(k + 3) * 300 + c];
#pragma unroll
                for (int n = 0; n < NBLK; n++) {
                    float4 h4 = *(const float4*)&h[b][n * BSZ + k];
                    acc[n] += h4.x * w0 + h4.y * w1 + h4.z * w2 + h4.w * w3;
                }
            }
#pragma unroll
            for (int n = 0; n < NBLK; n++) hg[b][n][c] = acc[n];
        }
        __syncthreads();
        // ---- P2: GRU -> hn (1200 items, hn into hg cols [0,100)); rank top-4 (12 thr)
        for (int idx = tid; idx < 1200; idx += 640) {
            int b = idx / 600, r = idx % 600, n = r / BSZ, c = r % BSZ;
            float p1 = p1s[b][n];
            float xr = p1 * u[b][c] + grub[c];
            float xz = p1 * u[b][BSZ + c] + grub[BSZ + c];
            float xn = p1 * u[b][2 * BSZ + c] + grub[2 * BSZ + c];
            float hr = hg[b][n][c], hz = hg[b][n][BSZ + c], hnn = hg[b][n][2 * BSZ + c];
            float r_ = 1.f / (1.f + expf(-(xr + hr)));
            float z_ = 1.f / (1.f + expf(-(xz + hz)));
            float nn = tanhf(xn + r_ * hnn);
            float hold = h[b][r];
            hg[b][n][c] = (1.f - z_) * nn + z_ * hold;
        }
        if (tid < 12) {
            int b = tid / 6, n = tid % 6;
            float pn = p1s[b][n];
            int cnt = 0;
            for (int j = 0; j < NBLK; j++) {
                float pj = p1s[b][j];
                if (pj > pn || (pj == pn && j < n)) cnt++;
            }
            float bm = (cnt < 4) ? 1.f : 0.f;
            bmv[b][n] = bm;
            bm_out[(size_t)(t * BATCH + b0 + b) * NBLK + n] = bm;
        }
        __syncthreads();
        // ---- P3: q2|k2 = hn @ [Wq2|Wk2]  (768 items, 1 acc each)
        for (int idx = tid; idx < 768; idx += 640) {
            int b = idx / 384, r = idx % 384, n = r >> 6, c = r & 63;
            const float* w = (c < 32) ? (Wq2 + c) : (Wk2 + (c - 32));
            float acc = 0.f;
            for (int k = 0; k < BSZ; k += 4) {
                float4 h4 = *(const float4*)&hg[b][n][k];
                acc += h4.x * w[(k)*32] + h4.y * w[(k + 1) * 32] +
                       h4.z * w[(k + 2) * 32] + h4.w * w[(k + 3) * 32];
            }
            qkv[b][n][c] = acc;   // q2 at [0,32), k2 at [32,64)
        }
        __syncthreads();
        // ---- P4: waves 0-1: p2 logits+softmax in-wave (36 lanes each, b = wave);
        //          tids 128..527: v2 = hn @ Wv2 (400 items x 3 accs)
        if (tid < 128) {
            int b = tid >> 6, l = tid & 63;
            if (l < 36) {
                int n = l / 6, m = l % 6;
                float e = 0.f;
                for (int d = 0; d < DC; d += 4) {
                    float4 q4 = *(const float4*)&qkv[b][n][d];
                    float4 k4 = *(const float4*)&qkv[b][m][32 + d];
                    e += q4.x * k4.x + q4.y * k4.y + q4.z * k4.z + q4.w * k4.w;
                }
                e *= 0.17677669529663687f;  // 1/sqrt(32)
                float ev[6];
#pragma unroll
                for (int j = 0; j < 6; j++) ev[j] = __shfl(e, n * 6 + j, 64);
                float mx = ev[0];
#pragma unroll
                for (int j = 1; j < 6; j++) mx = fmaxf(mx, ev[j]);
                float sum = 0.f;
#pragma unroll
                for (int j = 0; j < 6; j++) sum += expf(ev[j] - mx);
                p2s[b][n][m] = expf(e - mx) / sum;
            }
        } else if (tid < 528) {
            int idx = tid - 128;
            int b = idx / 200, g = (idx % 200) / 100, c = idx % 100;
            int nb = g * 3;
            float a0 = 0.f, a1 = 0.f, a2 = 0.f;
            for (int k = 0; k < BSZ; k += 4) {
                float w0 = Wv2[(k)*100 + c];
                float w1 = Wv2[(k + 1) * 100 + c];
                float w2 = Wv2[(k + 2) * 100 + c];
                float w3 = Wv2[(k + 3) * 100 + c];
                float4 h0 = *(const float4*)&hg[b][nb][k];
                float4 h1 = *(const float4*)&hg[b][nb + 1][k];
                float4 h2 = *(const float4*)&hg[b][nb + 2][k];
                a0 += h0.x * w0 + h0.y * w1 + h0.z * w2 + h0.w * w3;
                a1 += h1.x * w0 + h1.y * w1 + h1.z * w2 + h1.w * w3;
                a2 += h2.x * w0 + h2.y * w1 + h2.z * w2 + h2.w * w3;
            }
            qkv[b][nb][64 + c] = a0;
            qkv[b][nb + 1][64 + c] = a1;
            qkv[b][nb + 2][64 + c] = a2;
        }
        __syncthreads();
        // ---- P5: blend + writes; fold next-step mask into h; prefetch next KU row
        {
            float mvn0 = (t < T_STEPS - 1) ? masks[(t + 1) * BATCH + b0] : 1.f;
            float mvn1 = (t < T_STEPS - 1) ? masks[(t + 1) * BATCH + b0 + 1] : 1.f;
            for (int idx = tid; idx < 1200; idx += 640) {
                int b = idx / 600, r = idx % 600, n = r / BSZ, c = r % BSZ;
                float acc = hg[b][n][c];
#pragma unroll
                for (int m = 0; m < 6; m++) acc += p2s[b][n][m] * qkv[b][m][64 + c];
                float hold = h[b][r];
                float hnew = (bmv[b][n] != 0.f) ? acc : hold;
                h[b][r] = hnew * (b ? mvn1 : mvn0);
                size_t row = (size_t)(t * BATCH + b0 + b);
                outb[row * OUT_KP + r] = (bf16_t)hnew;
                if (t == T_STEPS - 1) hT_out[(size_t)(b0 + b) * NHID + r] = hnew;
            }
            if (tid < 16) {
                int b = tid >> 3;
                outb[(size_t)(t * BATCH + b0 + b) * OUT_KP + NHID + (tid & 7)] = (bf16_t)0.f;
            }
            if (t < T_STEPS - 1) {
                for (int idx = tid; idx < 728; idx += 640) {
                    int b = idx / 364, c = idx % 364;
                    float v = KU[(size_t)((t + 1) * BATCH + b0 + b) * KU_N + c];
                    if (c < DK) k1s[b][c] = v; else u[b][c - DK] = v;
                }
            }
        }
        __syncthreads();
    }
}

// ---------------- dec = outb @ decWT^T + dec_b (bf16 MFMA 16x16x32) ----------------
// M=32768 N=512 K=608. BM=128 BN=64 BK=32, 4 waves; wave: 2 m-tiles x 4 n-tiles.

__global__ __launch_bounds__(256) void dec_gemm(const bf16_t* __restrict__ Ag,
                                                const bf16_t* __restrict__ Bg,
                                                const float* __restrict__ bias,
                                                float* __restrict__ C) {
    __shared__ bf16_t As[128][32];
    __shared__ bf16_t Bs[64][32];
    const int tid = threadIdx.x;
    const int wave = tid >> 6, lane = tid & 63;
    const int m0 = blockIdx.x * 128, n0 = blockIdx.y * 64;
    f32x4 acc[2][4] = {};
    for (int k0 = 0; k0 < OUT_KP; k0 += 32) {
#pragma unroll
        for (int ii = 0; ii < 2; ii++) {
            int el = (tid + ii * 256) * 8;
            int row = el >> 5, col = el & 31;
            *(float4*)&As[row][col] = *(const float4*)(Ag + (size_t)(m0 + row) * OUT_KP + k0 + col);
        }
        {
            int el = tid * 8;
            int row = el >> 5, col = el & 31;
            *(float4*)&Bs[row][col] = *(const float4*)(Bg + (size_t)(n0 + row) * OUT_KP + k0 + col);
        }
        __syncthreads();
        const int fm = lane & 15, fq = (lane >> 4) * 8;
        bf16x8 a[2], bfr[4];
        a[0] = *(const bf16x8*)&As[wave * 32 + fm][fq];
        a[1] = *(const bf16x8*)&As[wave * 32 + 16 + fm][fq];
#pragma unroll
        for (int nt = 0; nt < 4; nt++) bfr[nt] = *(const bf16x8*)&Bs[nt * 16 + fm][fq];
#pragma unroll
        for (int mt = 0; mt < 2; mt++)
#pragma unroll
            for (int nt = 0; nt < 4; nt++)
                acc[mt][nt] = __builtin_amdgcn_mfma_f32_16x16x32_bf16(a[mt], bfr[nt], acc[mt][nt], 0, 0, 0);
        __syncthreads();
    }
    const int fm = lane & 15, fr = (lane >> 4) * 4;
#pragma unroll
    for (int mt = 0; mt < 2; mt++)
#pragma unroll
        for (int nt = 0; nt < 4; nt++) {
            int n = n0 + nt * 16 + fm;
            float bia = bias[n];
#pragma unroll
            for (int r = 0; r < 4; r++) {
                int m = m0 + wave * 32 + mt * 16 + fr + r;
                C[(size_t)m * NTOKC + n] = acc[mt][nt][r] + bia;
            }
        }
}

// ---------------- launch ----------------

extern "C" void kernel_launch(void* const* d_in, const int* in_sizes, int n_in,
                              void* d_out, int out_size, void* d_ws, size_t ws_size,
                              hipStream_t stream) {
    const float* input  = (const float*)d_in[0];
    const float* hidden = (const float*)d_in[1];
    const float* masks  = (const float*)d_in[2];
    const float* encW   = (const float*)d_in[3];
    const float* encB   = (const float*)d_in[4];
    const float* Wq     = (const float*)d_in[5];
    const float* Wk     = (const float*)d_in[6];
    const float* Wv     = (const float*)d_in[7];
    const float* Wx     = (const float*)d_in[8];
    const float* Wh     = (const float*)d_in[9];
    const float* grub   = (const float*)d_in[10];
    const float* Wq2    = (const float*)d_in[11];
    const float* Wk2    = (const float*)d_in[12];
    const float* Wv2    = (const float*)d_in[13];
    const float* decW   = (const float*)d_in[14];
    const float* decB   = (const float*)d_in[15];

    char* ws = (char*)d_ws;
    float*  KU    = (float*)(ws + WS_KU);
    bf16_t* outb  = (bf16_t*)(ws + WS_OUTB);
    float*  W1    = (float*)(ws + WS_W1);
    float*  b1    = (float*)(ws + WS_B1);
    float*  WvWx  = (float*)(ws + WS_WVWX);
    bf16_t* decWT = (bf16_t*)(ws + WS_DECWT);

    float* out_dec = (float*)d_out;
    float* out_hT  = out_dec + 16777216;   // T*B*NTOK
    float* out_bm  = out_dec + 17084416;   // + B*NHID

    prep_wvwx<<<(NINP * 300 + 255) / 256, 256, 0, stream>>>(Wv, Wx, WvWx);
    prep_w1<<<(NTOKC * KU_N + 255) / 256, 256, 0, stream>>>(encW, Wk, WvWx, W1);
    prep_b1<<<2, 256, 0, stream>>>(encB, Wk, WvWx, b1);
    prep_decwt<<<(NTOKC * OUT_KP + 255) / 256, 256, 0, stream>>>(decW, decWT);
    ku_gemm<<<dim3(256, 6), 256, 0, stream>>>(input, W1, b1, KU);
    scan_kernel<<<256, 640, 0, stream>>>(hidden, masks, Wq, Wh, grub, Wq2, Wk2, Wv2,
                                         KU, outb, out_hT, out_bm);
    dec_gemm<<<dim3(256, 8), 256, 0, stream>>>(outb, decWT, decB, out_dec);
}

// Round 4
// 3131.540 us; speedup vs baseline: 1.3323x; 1.3323x over previous
//
#include <hip/hip_runtime.h>
#include <hip/hip_bf16.h>
#include <stdint.h>

typedef __bf16 bf16_t;
typedef __bf16 bf16x8 __attribute__((ext_vector_type(8)));
typedef float f32x4 __attribute__((ext_vector_type(4)));

#define T_STEPS 64
#define BATCH   512
#define NTOKC   512
#define NINP    600
#define NHID    600
#define NBLK    6
#define BSZ     100
#define DK      64
#define ATTD    340
#define DC      32
#define KU_N    384     // 64 (k1) + 300 (u) + pad
#define OUT_KP  608     // NHID padded for dec GEMM K
#define W2_N    168     // 32 (q2) + 32 (k2) + 100 (v2) + pad

// workspace layout (bytes), all 16B aligned
#define WS_KU     0u                 // 32768*384*4  = 50331648
#define WS_OUTB   50331648u          // 32768*608*2  = 39845888
#define WS_W1     90177536u          // 512*384*4    = 786432
#define WS_B1     90963968u          // 384*4        = 1536
#define WS_WVWX   90965504u          // 600*300*4    = 720000 (dead after prep_b1;
                                     //   W2cat [100][168] overlaid here, 67200 B)
#define WS_DECWT  91685504u          // 512*608*2    = 622592  (end ~92.3 MB)

// ---------------- prep kernels (tiny fp32 GEMMs) ----------------

__global__ void prep_wvwx(const float* __restrict__ Wv, const float* __restrict__ Wx,
                          float* __restrict__ WvWx) {
    int idx = blockIdx.x * 256 + threadIdx.x;
    if (idx >= NINP * 300) return;
    int i = idx / 300, c = idx % 300;
    float acc = 0.f;
    for (int a = 0; a < ATTD; a++) acc += Wv[i * ATTD + a] * Wx[a * 300 + c];
    WvWx[i * 300 + c] = acc;
}

__global__ void prep_w1(const float* __restrict__ encW, const float* __restrict__ Wk,
                        const float* __restrict__ WvWx, float* __restrict__ W1) {
    int idx = blockIdx.x * 256 + threadIdx.x;
    if (idx >= NTOKC * KU_N) return;
    int i = idx / KU_N, c = idx % KU_N;
    float acc = 0.f;
    if (c < DK) {
        for (int k = 0; k < NINP; k++) acc += encW[i * NINP + k] * Wk[k * DK + c];
    } else if (c < DK + 300) {
        int cc = c - DK;
        for (int k = 0; k < NINP; k++) acc += encW[i * NINP + k] * WvWx[k * 300 + cc];
    }
    W1[idx] = acc;
}

__global__ void prep_b1(const float* __restrict__ encB, const float* __restrict__ Wk,
                        const float* __restrict__ WvWx, float* __restrict__ b1) {
    int c = blockIdx.x * 256 + threadIdx.x;
    if (c >= KU_N) return;
    float acc = 0.f;
    if (c < DK) {
        for (int k = 0; k < NINP; k++) acc += encB[k] * Wk[k * DK + c];
    } else if (c < DK + 300) {
        int cc = c - DK;
        for (int k = 0; k < NINP; k++) acc += encB[k] * WvWx[k * 300 + cc];
    }
    b1[c] = acc;
}

// pack [Wq2 | Wk2 | Wv2] -> W2cat[100][168] so scan p5 is branch-free
__global__ void prep_w2cat(const float* __restrict__ Wq2, const float* __restrict__ Wk2,
                           const float* __restrict__ Wv2, float* __restrict__ W2) {
    int idx = blockIdx.x * 256 + threadIdx.x;
    if (idx >= BSZ * W2_N) return;
    int k = idx / W2_N, c = idx % W2_N;
    float v = 0.f;
    if (c < 32) v = Wq2[k * 32 + c];
    else if (c < 64) v = Wk2[k * 32 + (c - 32)];
    else if (c < 164) v = Wv2[k * 100 + (c - 64)];
    W2[idx] = v;
}

__global__ void prep_decwt(const float* __restrict__ decW, bf16_t* __restrict__ decWT) {
    int idx = blockIdx.x * 256 + threadIdx.x;
    if (idx >= NTOKC * OUT_KP) return;
    int n = idx / OUT_KP, k = idx % OUT_KP;
    decWT[idx] = (k < NHID) ? (bf16_t)decW[k * NTOKC + n] : (bf16_t)0.f;
}

// ---------------- KU = input @ W1 + b1 (fp32; precision-critical) ----------------
// M=32768, K=512, N=384. BM=128 BN=64 BK=16, 256 thr, 8x4 per-thread tile.

__global__ __launch_bounds__(256) void ku_gemm(const float* __restrict__ A,
                                               const float* __restrict__ W1,
                                               const float* __restrict__ b1,
                                               float* __restrict__ KU) {
    __shared__ float As[16][128];
    __shared__ float Bs[16][64];
    const int tid = threadIdx.x;
    const int m0 = blockIdx.x * 128, n0 = blockIdx.y * 64;
    const int ty = tid >> 4, tx = tid & 15;
    const int bk = tid >> 6, bn = tid & 63;
    float acc[8][4] = {};
    for (int k0 = 0; k0 < NTOKC; k0 += 16) {
#pragma unroll
        for (int ii = 0; ii < 2; ii++) {
            int t2 = tid + ii * 256;
            int ar = t2 >> 2, ac4 = (t2 & 3) << 2;
            float4 raw = *(const float4*)(A + (size_t)(m0 + ar) * NTOKC + k0 + ac4);
            As[ac4 + 0][ar] = raw.x;
            As[ac4 + 1][ar] = raw.y;
            As[ac4 + 2][ar] = raw.z;
            As[ac4 + 3][ar] = raw.w;
        }
#pragma unroll
        for (int i = 0; i < 4; i++) {
            int kk = bk + (i << 2);
            Bs[kk][bn] = W1[(size_t)(k0 + kk) * KU_N + n0 + bn];
        }
        __syncthreads();
#pragma unroll
        for (int kk = 0; kk < 16; kk++) {
            float4 a0 = *(const float4*)&As[kk][ty * 8];
            float4 a1 = *(const float4*)&As[kk][ty * 8 + 4];
            float4 bv = *(const float4*)&Bs[kk][tx * 4];
            float av[8] = {a0.x, a0.y, a0.z, a0.w, a1.x, a1.y, a1.z, a1.w};
            float bw[4] = {bv.x, bv.y, bv.z, bv.w};
#pragma unroll
            for (int r = 0; r < 8; r++)
#pragma unroll
                for (int c = 0; c < 4; c++) acc[r][c] += av[r] * bw[c];
        }
        __syncthreads();
    }
#pragma unroll
    for (int r = 0; r < 8; r++) {
        int m = m0 + ty * 8 + r;
#pragma unroll
        for (int c = 0; c < 4; c++) {
            int n = n0 + tx * 4 + c;
            KU[(size_t)m * KU_N + n] = acc[r][c] + b1[n];
        }
    }
}

// ---------------- persistent scan: 1 WG per 2 batch elems, all 64 steps ----------------
// EXACT round-0 phase skeleton (grid 256 x 640 = 1 WG/CU lockstep; the L2-resident
// regime with FETCH ~27 MB depends on it — r1/r2/r3 restructures all collapsed it
// to 0.5-4.2 GB FETCH and ~3x slowdown). Local-only edits vs round 0:
//   (a) p5 reads packed W2cat (branch-free; was 3-way lane-divergent pointer select)
//   (b) p2a+p2b merged via in-wave __shfl (threads 0..11 share wave 0): one less
//       barrier per step, memory patterns untouched.

__global__ __launch_bounds__(640) void scan_kernel(
    const float* __restrict__ hidden, const float* __restrict__ masks,
    const float* __restrict__ Wq, const float* __restrict__ Wh,
    const float* __restrict__ grub, const float* __restrict__ W2cat,
    const float* __restrict__ KU, bf16_t* __restrict__ outb,
    float* __restrict__ hT_out, float* __restrict__ bm_out) {
    __shared__ float h[2][NHID];
    __shared__ float u[2][300];
    __shared__ float k1s[2][DK];
    __shared__ float qb[2][NBLK][DK];
    __shared__ float p1s[2][8], bmv[2][8];
    __shared__ float hg[2][NBLK][300];   // hg, then hn in cols [0,100)
    __shared__ float qkv[2][NBLK][164];  // q2|k2|v2
    __shared__ float p2s[2][NBLK][8];

    const int tid = threadIdx.x;
    const int b0 = blockIdx.x * 2;

    for (int idx = tid; idx < 2 * NHID; idx += 640) {
        int b = idx / NHID, j = idx % NHID;
        h[b][j] = hidden[(size_t)(b0 + b) * NHID + j];
    }
    __syncthreads();

    for (int t = 0; t < T_STEPS; t++) {
        // phase 0: mask h, load k1/u
        {
            float mv0 = masks[t * BATCH + b0];
            float mv1 = masks[t * BATCH + b0 + 1];
            for (int idx = tid; idx < 2 * NHID; idx += 640) {
                int b = idx / NHID, j = idx % NHID;
                h[b][j] *= (b ? mv1 : mv0);
            }
            for (int idx = tid; idx < 2 * 364; idx += 640) {
                int b = idx / 364, c = idx % 364;
                float v = KU[(size_t)(t * BATCH + b0 + b) * KU_N + c];
                if (c < DK) k1s[b][c] = v; else u[b][c - DK] = v;
            }
        }
        __syncthreads();
        // phase 1: q = hb @ Wq  (768 dots of 100)
        for (int idx = tid; idx < 2 * NBLK * DK; idx += 640) {
            int b = idx / (NBLK * DK), r = idx % (NBLK * DK);
            int n = r / DK, d = r % DK;
            float acc = 0.f;
            const float* hp = &h[b][n * BSZ];
            for (int k = 0; k < BSZ; k += 4) {
                float4 h4 = *(const float4*)(hp + k);
                acc += h4.x * Wq[(k)*DK + d];
                acc += h4.y * Wq[(k + 1) * DK + d];
                acc += h4.z * Wq[(k + 2) * DK + d];
                acc += h4.w * Wq[(k + 3) * DK + d];
            }
            qb[b][n][d] = acc;
        }
        __syncthreads();
        // phase 2 (merged 2a+2b): p1 score + stable top-4 rank, lanes 0..11 of wave 0
        if (tid < 2 * NBLK) {
            int b = tid / NBLK, n = tid % NBLK;
            float s = 0.f;
            for (int d = 0; d < DK; d++) s += qb[b][n][d] * k1s[b][d];
            s *= 0.125f;
            float mx = fmaxf(s, 0.f);
            float e0 = expf(0.f - mx), e1 = expf(s - mx);
            float p1 = e1 / (e0 + e1);
            p1s[b][n] = p1;
            int base = b * NBLK;
            int cnt = 0;
#pragma unroll
            for (int j = 0; j < NBLK; j++) {
                float pj = __shfl(p1, base + j, 64);
                if (pj > p1 || (pj == p1 && j < n)) cnt++;
            }
            float bm = (cnt < 4) ? 1.f : 0.f;
            bmv[b][n] = bm;
            bm_out[(size_t)(t * BATCH + b0 + b) * NBLK + n] = bm;
        }
        __syncthreads();
        // phase 3: hg = hb @ Wh  (outer product, 600 lanes own (b,c), 6 accs)
        for (int idx = tid; idx < 600; idx += 640) {
            int b = idx / 300, c = idx % 300;
            float acc[NBLK] = {};
            for (int k = 0; k < BSZ; k += 4) {
                float w0 = Wh[(k)*300 + c];
                float w1 = Wh[(k + 1) * 300 + c];
                float w2 = Wh[(k + 2) * 300 + c];
                float w3 = Wh[(k + 3) * 300 + c];
#pragma unroll
                for (int n = 0; n < NBLK; n++) {
                    float4 h4 = *(const float4*)&h[b][n * BSZ + k];
                    acc[n] += h4.x * w0 + h4.y * w1 + h4.z * w2 + h4.w * w3;
                }
            }
#pragma unroll
            for (int n = 0; n < NBLK; n++) hg[b][n][c] = acc[n];
        }
        __syncthreads();
        // phase 4: GRU -> hn (written into hg cols [0,100))
        for (int idx = tid; idx < 1200; idx += 640) {
            int b = idx / 600, r = idx % 600, n = r / BSZ, c = r % BSZ;
            float p1 = p1s[b][n];
            float xr = p1 * u[b][c] + grub[c];
            float xz = p1 * u[b][BSZ + c] + grub[BSZ + c];
            float xn = p1 * u[b][2 * BSZ + c] + grub[2 * BSZ + c];
            float hr = hg[b][n][c], hz = hg[b][n][BSZ + c], hnn = hg[b][n][2 * BSZ + c];
            float r_ = 1.f / (1.f + expf(-(xr + hr)));
            float z_ = 1.f / (1.f + expf(-(xz + hz)));
            float nn = tanhf(xn + r_ * hnn);
            float hold = h[b][n * BSZ + c];
            hg[b][n][c] = (1.f - z_) * nn + z_ * hold;
        }
        __syncthreads();
        // phase 5: q2|k2|v2 = hn @ W2cat (branch-free packed weights)
        for (int idx = tid; idx < 2 * 164; idx += 640) {
            int b = idx / 164, c = idx % 164;
            const float* w = W2cat + c;
            float acc[NBLK] = {};
            for (int k = 0; k < BSZ; k += 4) {
                float w0 = w[(k)*W2_N];
                float w1 = w[(k + 1) * W2_N];
                float w2 = w[(k + 2) * W2_N];
                float w3 = w[(k + 3) * W2_N];
#pragma unroll
                for (int n = 0; n < NBLK; n++) {
                    float4 h4 = *(const float4*)&hg[b][n][k];
                    acc[n] += h4.x * w0 + h4.y * w1 + h4.z * w2 + h4.w * w3;
                }
            }
#pragma unroll
            for (int n = 0; n < NBLK; n++) qkv[b][n][c] = acc[n];
        }
        __syncthreads();
        // phase 6a: p2 logits
        if (tid < 72) {
            int b = tid / 36, r = tid % 36, n = r / 6, m = r % 6;
            float e = 0.f;
            for (int d = 0; d < DC; d++) e += qkv[b][n][d] * qkv[b][m][32 + d];
            p2s[b][n][m] = e * 0.17677669529663687f;  // 1/sqrt(32)
        }
        __syncthreads();
        // phase 6b: softmax rows
        if (tid < 12) {
            int b = tid / 6, n = tid % 6;
            float mx = p2s[b][n][0];
            for (int m = 1; m < 6; m++) mx = fmaxf(mx, p2s[b][n][m]);
            float ev[6], sum = 0.f;
            for (int m = 0; m < 6; m++) { ev[m] = expf(p2s[b][n][m] - mx); sum += ev[m]; }
            for (int m = 0; m < 6; m++) p2s[b][n][m] = ev[m] / sum;
        }
        __syncthreads();
        // phase 7: hc = hn + p2@v2, blend by bmask, write h/outb/hT
        for (int idx = tid; idx < 1200; idx += 640) {
            int b = idx / 600, r = idx % 600, n = r / BSZ, c = r % BSZ;
            float acc = hg[b][n][c];
#pragma unroll
            for (int m = 0; m < 6; m++) acc += p2s[b][n][m] * qkv[b][m][64 + c];
            float hold = h[b][n * BSZ + c];
            float hnew = (bmv[b][n] != 0.f) ? acc : hold;
            h[b][n * BSZ + c] = hnew;
            size_t row = (size_t)(t * BATCH + b0 + b);
            outb[row * OUT_KP + n * BSZ + c] = (bf16_t)hnew;
            if (t == T_STEPS - 1) hT_out[(size_t)(b0 + b) * NHID + n * BSZ + c] = hnew;
        }
        for (int idx = tid; idx < 2 * 8; idx += 640) {
            int b = idx / 8, c = idx % 8;
            outb[(size_t)(t * BATCH + b0 + b) * OUT_KP + NHID + c] = (bf16_t)0.f;
        }
        __syncthreads();
    }
}

// ---------------- dec = outb @ decWT^T + dec_b (bf16 MFMA 16x16x32) ----------------
// M=32768 N=512 K=608. BM=128 BN=64 BK=32, 4 waves; wave: 2 m-tiles x 4 n-tiles.

__global__ __launch_bounds__(256) void dec_gemm(const bf16_t* __restrict__ Ag,
                                                const bf16_t* __restrict__ Bg,
                                                const float* __restrict__ bias,
                                                float* __restrict__ C) {
    __shared__ bf16_t As[128][32];
    __shared__ bf16_t Bs[64][32];
    const int tid = threadIdx.x;
    const int wave = tid >> 6, lane = tid & 63;
    const int m0 = blockIdx.x * 128, n0 = blockIdx.y * 64;
    f32x4 acc[2][4] = {};
    for (int k0 = 0; k0 < OUT_KP; k0 += 32) {
#pragma unroll
        for (int ii = 0; ii < 2; ii++) {
            int el = (tid + ii * 256) * 8;
            int row = el >> 5, col = el & 31;
            *(float4*)&As[row][col] = *(const float4*)(Ag + (size_t)(m0 + row) * OUT_KP + k0 + col);
        }
        {
            int el = tid * 8;
            int row = el >> 5, col = el & 31;
            *(float4*)&Bs[row][col] = *(const float4*)(Bg + (size_t)(n0 + row) * OUT_KP + k0 + col);
        }
        __syncthreads();
        const int fm = lane & 15, fq = (lane >> 4) * 8;
        bf16x8 a[2], bfr[4];
        a[0] = *(const bf16x8*)&As[wave * 32 + fm][fq];
        a[1] = *(const bf16x8*)&As[wave * 32 + 16 + fm][fq];
#pragma unroll
        for (int nt = 0; nt < 4; nt++) bfr[nt] = *(const bf16x8*)&Bs[nt * 16 + fm][fq];
#pragma unroll
        for (int mt = 0; mt < 2; mt++)
#pragma unroll
            for (int nt = 0; nt < 4; nt++)
                acc[mt][nt] = __builtin_amdgcn_mfma_f32_16x16x32_bf16(a[mt], bfr[nt], acc[mt][nt], 0, 0, 0);
        __syncthreads();
    }
    const int fm = lane & 15, fr = (lane >> 4) * 4;
#pragma unroll
    for (int mt = 0; mt < 2; mt++)
#pragma unroll
        for (int nt = 0; nt < 4; nt++) {
            int n = n0 + nt * 16 + fm;
            float bia = bias[n];
#pragma unroll
            for (int r = 0; r < 4; r++) {
                int m = m0 + wave * 32 + mt * 16 + fr + r;
                C[(size_t)m * NTOKC + n] = acc[mt][nt][r] + bia;
            }
        }
}

// ---------------- launch ----------------

extern "C" void kernel_launch(void* const* d_in, const int* in_sizes, int n_in,
                              void* d_out, int out_size, void* d_ws, size_t ws_size,
                              hipStream_t stream) {
    const float* input  = (const float*)d_in[0];
    const float* hidden = (const float*)d_in[1];
    const float* masks  = (const float*)d_in[2];
    const float* encW   = (const float*)d_in[3];
    const float* encB   = (const float*)d_in[4];
    const float* Wq     = (const float*)d_in[5];
    const float* Wk     = (const float*)d_in[6];
    const float* Wv     = (const float*)d_in[7];
    const float* Wx     = (const float*)d_in[8];
    const float* Wh     = (const float*)d_in[9];
    const float* grub   = (const float*)d_in[10];
    const float* Wq2    = (const float*)d_in[11];
    const float* Wk2    = (const float*)d_in[12];
    const float* Wv2    = (const float*)d_in[13];
    const float* decW   = (const float*)d_in[14];
    const float* decB   = (const float*)d_in[15];

    char* ws = (char*)d_ws;
    float*  KU    = (float*)(ws + WS_KU);
    bf16_t* outb  = (bf16_t*)(ws + WS_OUTB);
    float*  W1    = (float*)(ws + WS_W1);
    float*  b1    = (float*)(ws + WS_B1);
    float*  WvWx  = (float*)(ws + WS_WVWX);
    float*  W2cat = (float*)(ws + WS_WVWX);   // overlays WvWx (dead after prep_b1)
    bf16_t* decWT = (bf16_t*)(ws + WS_DECWT);

    float* out_dec = (float*)d_out;
    float* out_hT  = out_dec + 16777216;   // T*B*NTOK
    float* out_bm  = out_dec + 17084416;   // + B*NHID

    prep_wvwx<<<(NINP * 300 + 255) / 256, 256, 0, stream>>>(Wv, Wx, WvWx);
    prep_w1<<<(NTOKC * KU_N + 255) / 256, 256, 0, stream>>>(encW, Wk, WvWx, W1);
    prep_b1<<<2, 256, 0, stream>>>(encB, Wk, WvWx, b1);
    prep_w2cat<<<(BSZ * W2_N + 255) / 256, 256, 0, stream>>>(Wq2, Wk2, Wv2, W2cat);
    prep_decwt<<<(NTOKC * OUT_KP + 255) / 256, 256, 0, stream>>>(decW, decWT);
    ku_gemm<<<dim3(256, 6), 256, 0, stream>>>(input, W1, b1, KU);
    scan_kernel<<<256, 640, 0, stream>>>(hidden, masks, Wq, Wh, grub, W2cat,
                                         KU, outb, out_hT, out_bm);
    dec_gemm<<<dim3(256, 8), 256, 0, stream>>>(outb, decWT, decB, out_dec);
}

// Round 5
// 2037.687 us; speedup vs baseline: 2.0476x; 1.5368x over previous
//
#include <hip/hip_runtime.h>
#include <hip/hip_bf16.h>
#include <stdint.h>

typedef __bf16 bf16_t;
typedef __bf16 bf16x8 __attribute__((ext_vector_type(8)));
typedef float f32x4 __attribute__((ext_vector_type(4)));

#define T_STEPS 64
#define BATCH   512
#define NTOKC   512
#define NINP    600
#define NHID    600
#define NBLK    6
#define BSZ     100
#define DK      64
#define ATTD    340
#define DC      32
#define KU_N    384     // 64 (k1) + 300 (u) + pad
#define OUT_KP  608     // NHID padded for dec GEMM K

// workspace layout (bytes), all 16B aligned
#define WS_KU     0u                 // 32768*384*4  = 50331648
#define WS_OUTB   50331648u          // 32768*608*2  = 39845888
#define WS_W1     90177536u          // 512*384*4    = 786432
#define WS_B1     90963968u          // 384*4        = 1536
#define WS_WVWX   90965504u          // 600*300*4    = 720000
#define WS_DECWT  91685504u          // 512*608*2    = 622592  (end ~92.3 MB)

// ---------------- prep kernels (tiny fp32 GEMMs) ----------------

__global__ void prep_wvwx(const float* __restrict__ Wv, const float* __restrict__ Wx,
                          float* __restrict__ WvWx) {
    int idx = blockIdx.x * 256 + threadIdx.x;
    if (idx >= NINP * 300) return;
    int i = idx / 300, c = idx % 300;
    float acc = 0.f;
    for (int a = 0; a < ATTD; a++) acc += Wv[i * ATTD + a] * Wx[a * 300 + c];
    WvWx[i * 300 + c] = acc;
}

__global__ void prep_w1(const float* __restrict__ encW, const float* __restrict__ Wk,
                        const float* __restrict__ WvWx, float* __restrict__ W1) {
    int idx = blockIdx.x * 256 + threadIdx.x;
    if (idx >= NTOKC * KU_N) return;
    int i = idx / KU_N, c = idx % KU_N;
    float acc = 0.f;
    if (c < DK) {
        for (int k = 0; k < NINP; k++) acc += encW[i * NINP + k] * Wk[k * DK + c];
    } else if (c < DK + 300) {
        int cc = c - DK;
        for (int k = 0; k < NINP; k++) acc += encW[i * NINP + k] * WvWx[k * 300 + cc];
    }
    W1[idx] = acc;
}

__global__ void prep_b1(const float* __restrict__ encB, const float* __restrict__ Wk,
                        const float* __restrict__ WvWx, float* __restrict__ b1) {
    int c = blockIdx.x * 256 + threadIdx.x;
    if (c >= KU_N) return;
    float acc = 0.f;
    if (c < DK) {
        for (int k = 0; k < NINP; k++) acc += encB[k] * Wk[k * DK + c];
    } else if (c < DK + 300) {
        int cc = c - DK;
        for (int k = 0; k < NINP; k++) acc += encB[k] * WvWx[k * 300 + cc];
    }
    b1[c] = acc;
}

__global__ void prep_decwt(const float* __restrict__ decW, bf16_t* __restrict__ decWT) {
    int idx = blockIdx.x * 256 + threadIdx.x;
    if (idx >= NTOKC * OUT_KP) return;
    int n = idx / OUT_KP, k = idx % OUT_KP;
    decWT[idx] = (k < NHID) ? (bf16_t)decW[k * NTOKC + n] : (bf16_t)0.f;
}

// ---------------- KU = input @ W1 + b1 (fp32; precision-critical) ----------------
// M=32768, K=512, N=384. BM=128 BN=64 BK=16, 256 thr, 8x4 per-thread tile.

__global__ __launch_bounds__(256) void ku_gemm(const float* __restrict__ A,
                                               const float* __restrict__ W1,
                                               const float* __restrict__ b1,
                                               float* __restrict__ KU) {
    __shared__ float As[16][128];
    __shared__ float Bs[16][64];
    const int tid = threadIdx.x;
    const int m0 = blockIdx.x * 128, n0 = blockIdx.y * 64;
    const int ty = tid >> 4, tx = tid & 15;
    const int bk = tid >> 6, bn = tid & 63;
    float acc[8][4] = {};
    for (int k0 = 0; k0 < NTOKC; k0 += 16) {
#pragma unroll
        for (int ii = 0; ii < 2; ii++) {
            int t2 = tid + ii * 256;
            int ar = t2 >> 2, ac4 = (t2 & 3) << 2;
            float4 raw = *(const float4*)(A + (size_t)(m0 + ar) * NTOKC + k0 + ac4);
            As[ac4 + 0][ar] = raw.x;
            As[ac4 + 1][ar] = raw.y;
            As[ac4 + 2][ar] = raw.z;
            As[ac4 + 3][ar] = raw.w;
        }
#pragma unroll
        for (int i = 0; i < 4; i++) {
            int kk = bk + (i << 2);
            Bs[kk][bn] = W1[(size_t)(k0 + kk) * KU_N + n0 + bn];
        }
        __syncthreads();
#pragma unroll
        for (int kk = 0; kk < 16; kk++) {
            float4 a0 = *(const float4*)&As[kk][ty * 8];
            float4 a1 = *(const float4*)&As[kk][ty * 8 + 4];
            float4 bv = *(const float4*)&Bs[kk][tx * 4];
            float av[8] = {a0.x, a0.y, a0.z, a0.w, a1.x, a1.y, a1.z, a1.w};
            float bw[4] = {bv.x, bv.y, bv.z, bv.w};
#pragma unroll
            for (int r = 0; r < 8; r++)
#pragma unroll
                for (int c = 0; c < 4; c++) acc[r][c] += av[r] * bw[c];
        }
        __syncthreads();
    }
#pragma unroll
    for (int r = 0; r < 8; r++) {
        int m = m0 + ty * 8 + r;
#pragma unroll
        for (int c = 0; c < 4; c++) {
            int n = n0 + tx * 4 + c;
            KU[(size_t)m * KU_N + n] = acc[r][c] + b1[n];
        }
    }
}

// ---------------- persistent scan: 1 WG per 2 batch elems, all 64 steps ----------------
// EXACT round-0 kernel (the only variant measured in the fast cache regime:
// FETCH 27 MB, 1314 us) with ONE change: Wh (120 KB, the dominant per-step
// global stream) is staged into LDS once at entry, making phase 3 immune to
// cross-block L2 timing. Everything else byte-identical to round 0.

__global__ __launch_bounds__(640) void scan_kernel(
    const float* __restrict__ hidden, const float* __restrict__ masks,
    const float* __restrict__ Wq, const float* __restrict__ Wh,
    const float* __restrict__ grub, const float* __restrict__ Wq2,
    const float* __restrict__ Wk2, const float* __restrict__ Wv2,
    const float* __restrict__ KU, bf16_t* __restrict__ outb,
    float* __restrict__ hT_out, float* __restrict__ bm_out) {
    __shared__ float h[2][NHID];
    __shared__ float u[2][300];
    __shared__ float k1s[2][DK];
    __shared__ float qb[2][NBLK][DK];
    __shared__ float p1s[2][8], bmv[2][8];
    __shared__ float hg[2][NBLK][300];   // hg, then hn in cols [0,100)
    __shared__ float qkv[2][NBLK][164];  // q2|k2|v2
    __shared__ float p2s[2][NBLK][8];
    __shared__ float Whs[BSZ * 300];     // staged Wh (120 KB)

    const int tid = threadIdx.x;
    const int b0 = blockIdx.x * 2;

    for (int idx = tid; idx < 2 * NHID; idx += 640) {
        int b = idx / NHID, j = idx % NHID;
        h[b][j] = hidden[(size_t)(b0 + b) * NHID + j];
    }
    for (int idx = tid; idx < BSZ * 300; idx += 640) Whs[idx] = Wh[idx];
    __syncthreads();

    for (int t = 0; t < T_STEPS; t++) {
        // phase 0: mask h, load k1/u
        {
            float mv0 = masks[t * BATCH + b0];
            float mv1 = masks[t * BATCH + b0 + 1];
            for (int idx = tid; idx < 2 * NHID; idx += 640) {
                int b = idx / NHID, j = idx % NHID;
                h[b][j] *= (b ? mv1 : mv0);
            }
            for (int idx = tid; idx < 2 * 364; idx += 640) {
                int b = idx / 364, c = idx % 364;
                float v = KU[(size_t)(t * BATCH + b0 + b) * KU_N + c];
                if (c < DK) k1s[b][c] = v; else u[b][c - DK] = v;
            }
        }
        __syncthreads();
        // phase 1: q = hb @ Wq  (768 dots of 100)
        for (int idx = tid; idx < 2 * NBLK * DK; idx += 640) {
            int b = idx / (NBLK * DK), r = idx % (NBLK * DK);
            int n = r / DK, d = r % DK;
            float acc = 0.f;
            const float* hp = &h[b][n * BSZ];
            for (int k = 0; k < BSZ; k += 4) {
                float4 h4 = *(const float4*)(hp + k);
                acc += h4.x * Wq[(k)*DK + d];
                acc += h4.y * Wq[(k + 1) * DK + d];
                acc += h4.z * Wq[(k + 2) * DK + d];
                acc += h4.w * Wq[(k + 3) * DK + d];
            }
            qb[b][n][d] = acc;
        }
        __syncthreads();
        // phase 2a: p1 = softmax([0,s])[1]  (s0 is exactly 0: src[0]=zeros)
        if (tid < 2 * NBLK) {
            int b = tid / NBLK, n = tid % NBLK;
            float s = 0.f;
            for (int d = 0; d < DK; d++) s += qb[b][n][d] * k1s[b][d];
            s *= 0.125f;
            float mx = fmaxf(s, 0.f);
            float e0 = expf(0.f - mx), e1 = expf(s - mx);
            p1s[b][n] = e1 / (e0 + e1);
        }
        __syncthreads();
        // phase 2b: stable top-4 mask (rank by p1, ties -> lower index, = lax.top_k)
        if (tid < 2 * NBLK) {
            int b = tid / NBLK, n = tid % NBLK;
            float pn = p1s[b][n];
            int cnt = 0;
            for (int j = 0; j < NBLK; j++) {
                float pj = p1s[b][j];
                if (pj > pn || (pj == pn && j < n)) cnt++;
            }
            float bm = (cnt < 4) ? 1.f : 0.f;
            bmv[b][n] = bm;
            bm_out[(size_t)(t * BATCH + b0 + b) * NBLK + n] = bm;
        }
        __syncthreads();
        // phase 3: hg = hb @ Wh  (outer product, 600 lanes own (b,c), 6 accs) — Wh from LDS
        for (int idx = tid; idx < 600; idx += 640) {
            int b = idx / 300, c = idx % 300;
            float acc[NBLK] = {};
            for (int k = 0; k < BSZ; k += 4) {
                float w0 = Whs[(k)*300 + c];
                float w1 = Whs[(k + 1) * 300 + c];
                float w2 = Whs[(k + 2) * 300 + c];
                float w3 = Whs[(k + 3) * 300 + c];
#pragma unroll
                for (int n = 0; n < NBLK; n++) {
                    float4 h4 = *(const float4*)&h[b][n * BSZ + k];
                    acc[n] += h4.x * w0 + h4.y * w1 + h4.z * w2 + h4.w * w3;
                }
            }
#pragma unroll
            for (int n = 0; n < NBLK; n++) hg[b][n][c] = acc[n];
        }
        __syncthreads();
        // phase 4: GRU -> hn (written into hg cols [0,100))
        for (int idx = tid; idx < 1200; idx += 640) {
            int b = idx / 600, r = idx % 600, n = r / BSZ, c = r % BSZ;
            float p1 = p1s[b][n];
            float xr = p1 * u[b][c] + grub[c];
            float xz = p1 * u[b][BSZ + c] + grub[BSZ + c];
            float xn = p1 * u[b][2 * BSZ + c] + grub[2 * BSZ + c];
            float hr = hg[b][n][c], hz = hg[b][n][BSZ + c], hnn = hg[b][n][2 * BSZ + c];
            float r_ = 1.f / (1.f + expf(-(xr + hr)));
            float z_ = 1.f / (1.f + expf(-(xz + hz)));
            float nn = tanhf(xn + r_ * hnn);
            float hold = h[b][n * BSZ + c];
            hg[b][n][c] = (1.f - z_) * nn + z_ * hold;
        }
        __syncthreads();
        // phase 5: q2|k2|v2 = hn @ [Wq2|Wk2|Wv2]
        for (int idx = tid; idx < 2 * 164; idx += 640) {
            int b = idx / 164, c = idx % 164;
            float acc[NBLK] = {};
            for (int k = 0; k < BSZ; k += 4) {
                float w0, w1, w2, w3;
                if (c < 32) {
                    w0 = Wq2[(k)*32 + c]; w1 = Wq2[(k + 1) * 32 + c];
                    w2 = Wq2[(k + 2) * 32 + c]; w3 = Wq2[(k + 3) * 32 + c];
                } else if (c < 64) {
                    int cc = c - 32;
                    w0 = Wk2[(k)*32 + cc]; w1 = Wk2[(k + 1) * 32 + cc];
                    w2 = Wk2[(k + 2) * 32 + cc]; w3 = Wk2[(k + 3) * 32 + cc];
                } else {
                    int cc = c - 64;
                    w0 = Wv2[(k)*100 + cc]; w1 = Wv2[(k + 1) * 100 + cc];
                    w2 = Wv2[(k + 2) * 100 + cc]; w3 = Wv2[(k + 3) * 100 + cc];
                }
#pragma unroll
                for (int n = 0; n < NBLK; n++) {
                    float4 h4 = *(const float4*)&hg[b][n][k];
                    acc[n] += h4.x * w0 + h4.y * w1 + h4.z * w2 + h4.w * w3;
                }
            }
#pragma unroll
            for (int n = 0; n < NBLK; n++) qkv[b][n][c] = acc[n];
        }
        __syncthreads();
        // phase 6a: p2 logits
        if (tid < 72) {
            int b = tid / 36, r = tid % 36, n = r / 6, m = r % 6;
            float e = 0.f;
            for (int d = 0; d < DC; d++) e += qkv[b][n][d] * qkv[b][m][32 + d];
            p2s[b][n][m] = e * 0.17677669529663687f;  // 1/sqrt(32)
        }
        __syncthreads();
        // phase 6b: softmax rows
        if (tid < 12) {
            int b = tid / 6, n = tid % 6;
            float mx = p2s[b][n][0];
            for (int m = 1; m < 6; m++) mx = fmaxf(mx, p2s[b][n][m]);
            float ev[6], sum = 0.f;
            for (int m = 0; m < 6; m++) { ev[m] = expf(p2s[b][n][m] - mx); sum += ev[m]; }
            for (int m = 0; m < 6; m++) p2s[b][n][m] = ev[m] / sum;
        }
        __syncthreads();
        // phase 7: hc = hn + p2@v2, blend by bmask, write h/outb/hT
        for (int idx = tid; idx < 1200; idx += 640) {
            int b = idx / 600, r = idx % 600, n = r / BSZ, c = r % BSZ;
            float acc = hg[b][n][c];
#pragma unroll
            for (int m = 0; m < 6; m++) acc += p2s[b][n][m] * qkv[b][m][64 + c];
            float hold = h[b][n * BSZ + c];
            float hnew = (bmv[b][n] != 0.f) ? acc : hold;
            h[b][n * BSZ + c] = hnew;
            size_t row = (size_t)(t * BATCH + b0 + b);
            outb[row * OUT_KP + n * BSZ + c] = (bf16_t)hnew;
            if (t == T_STEPS - 1) hT_out[(size_t)(b0 + b) * NHID + n * BSZ + c] = hnew;
        }
        for (int idx = tid; idx < 2 * 8; idx += 640) {
            int b = idx / 8, c = idx % 8;
            outb[(size_t)(t * BATCH + b0 + b) * OUT_KP + NHID + c] = (bf16_t)0.f;
        }
        __syncthreads();
    }
}

// ---------------- dec = outb @ decWT^T + dec_b (bf16 MFMA 16x16x32) ----------------
// M=32768 N=512 K=608. BM=128 BN=64 BK=32, 4 waves; wave: 2 m-tiles x 4 n-tiles.

__global__ __launch_bounds__(256) void dec_gemm(const bf16_t* __restrict__ Ag,
                                                const bf16_t* __restrict__ Bg,
                                                const float* __restrict__ bias,
                                                float* __restrict__ C) {
    __shared__ bf16_t As[128][32];
    __shared__ bf16_t Bs[64][32];
    const int tid = threadIdx.x;
    const int wave = tid >> 6, lane = tid & 63;
    const int m0 = blockIdx.x * 128, n0 = blockIdx.y * 64;
    f32x4 acc[2][4] = {};
    for (int k0 = 0; k0 < OUT_KP; k0 += 32) {
#pragma unroll
        for (int ii = 0; ii < 2; ii++) {
            int el = (tid + ii * 256) * 8;
            int row = el >> 5, col = el & 31;
            *(float4*)&As[row][col] = *(const float4*)(Ag + (size_t)(m0 + row) * OUT_KP + k0 + col);
        }
        {
            int el = tid * 8;
            int row = el >> 5, col = el & 31;
            *(float4*)&Bs[row][col] = *(const float4*)(Bg + (size_t)(n0 + row) * OUT_KP + k0 + col);
        }
        __syncthreads();
        const int fm = lane & 15, fq = (lane >> 4) * 8;
        bf16x8 a[2], bfr[4];
        a[0] = *(const bf16x8*)&As[wave * 32 + fm][fq];
        a[1] = *(const bf16x8*)&As[wave * 32 + 16 + fm][fq];
#pragma unroll
        for (int nt = 0; nt < 4; nt++) bfr[nt] = *(const bf16x8*)&Bs[nt * 16 + fm][fq];
#pragma unroll
        for (int mt = 0; mt < 2; mt++)
#pragma unroll
            for (int nt = 0; nt < 4; nt++)
                acc[mt][nt] = __builtin_amdgcn_mfma_f32_16x16x32_bf16(a[mt], bfr[nt], acc[mt][nt], 0, 0, 0);
        __syncthreads();
    }
    const int fm = lane & 15, fr = (lane >> 4) * 4;
#pragma unroll
    for (int mt = 0; mt < 2; mt++)
#pragma unroll
        for (int nt = 0; nt < 4; nt++) {
            int n = n0 + nt * 16 + fm;
            float bia = bias[n];
#pragma unroll
            for (int r = 0; r < 4; r++) {
                int m = m0 + wave * 32 + mt * 16 + fr + r;
                C[(size_t)m * NTOKC + n] = acc[mt][nt][r] + bia;
            }
        }
}

// ---------------- launch ----------------

extern "C" void kernel_launch(void* const* d_in, const int* in_sizes, int n_in,
                              void* d_out, int out_size, void* d_ws, size_t ws_size,
                              hipStream_t stream) {
    const float* input  = (const float*)d_in[0];
    const float* hidden = (const float*)d_in[1];
    const float* masks  = (const float*)d_in[2];
    const float* encW   = (const float*)d_in[3];
    const float* encB   = (const float*)d_in[4];
    const float* Wq     = (const float*)d_in[5];
    const float* Wk     = (const float*)d_in[6];
    const float* Wv     = (const float*)d_in[7];
    const float* Wx     = (const float*)d_in[8];
    const float* Wh     = (const float*)d_in[9];
    const float* grub   = (const float*)d_in[10];
    const float* Wq2    = (const float*)d_in[11];
    const float* Wk2    = (const float*)d_in[12];
    const float* Wv2    = (const float*)d_in[13];
    const float* decW   = (const float*)d_in[14];
    const float* decB   = (const float*)d_in[15];

    char* ws = (char*)d_ws;
    float*  KU    = (float*)(ws + WS_KU);
    bf16_t* outb  = (bf16_t*)(ws + WS_OUTB);
    float*  W1    = (float*)(ws + WS_W1);
    float*  b1    = (float*)(ws + WS_B1);
    float*  WvWx  = (float*)(ws + WS_WVWX);
    bf16_t* decWT = (bf16_t*)(ws + WS_DECWT);

    float* out_dec = (float*)d_out;
    float* out_hT  = out_dec + 16777216;   // T*B*NTOK
    float* out_bm  = out_dec + 17084416;   // + B*NHID

    prep_wvwx<<<(NINP * 300 + 255) / 256, 256, 0, stream>>>(Wv, Wx, WvWx);
    prep_w1<<<(NTOKC * KU_N + 255) / 256, 256, 0, stream>>>(encW, Wk, WvWx, W1);
    prep_b1<<<2, 256, 0, stream>>>(encB, Wk, WvWx, b1);
    prep_decwt<<<(NTOKC * OUT_KP + 255) / 256, 256, 0, stream>>>(decW, decWT);
    ku_gemm<<<dim3(256, 6), 256, 0, stream>>>(input, W1, b1, KU);
    scan_kernel<<<256, 640, 0, stream>>>(hidden, masks, Wq, Wh, grub, Wq2, Wk2, Wv2,
                                         KU, outb, out_hT, out_bm);
    dec_gemm<<<dim3(256, 8), 256, 0, stream>>>(outb, decWT, decB, out_dec);
}